// Round 9
// baseline (58.719 us; speedup 1.0000x reference)
//
#include <hip/hip_runtime.h>
#include <math.h>

// ArcFace fused loss, B=512, C=100000, float32.
// loss_b = logsumexp_c(64*arcrow) - 64*theta_valid ; out = mean_b loss_b
// Phase A: EARLY-EXIT one-hot scan, 2 NT loads issued BEFORE the LDS flag poll
//   (poll latency hides under the loads; exit lag <= 2 iters = 32 KB/block).
//   Nontemporal keeps y out of L3 so x (200 MB < 256 MB) stays L3-resident.
// Phase B: pure exp2 sum over x.
// Mean via one device-scope atomicAdd per block into d_out, zeroed by a
// captured hipMemsetAsync node each call (no cross-replay accumulation).

#define BB 512
#define CC 100000
#define C4 (CC / 4)           // 25000 float4 per row
#define BLK 1024

// 64 * log2(e), for exp(64x-64) = exp2(K*x - K)
#define K64 92.33248261689366f

typedef unsigned int u32x4 __attribute__((ext_vector_type(4)));
typedef float f32x4 __attribute__((ext_vector_type(4)));

__device__ __forceinline__ float wave_reduce_add(float v) {
    #pragma unroll
    for (int off = 32; off > 0; off >>= 1)
        v += __shfl_down(v, off, 64);
    return v;
}

__device__ __forceinline__ float e64(float x) {
    return __builtin_amdgcn_exp2f(fmaf(K64, x, -K64));   // v_exp_f32
}

__global__ __launch_bounds__(BLK) void arcface_rows(const float* __restrict__ y_true,
                                                    const float* __restrict__ logits,
                                                    float* __restrict__ out) {
    const int row = blockIdx.x;
    const int tid = threadIdx.x;
    const u32x4* __restrict__ y4 = (const u32x4*)(y_true + (size_t)row * CC);
    const f32x4* __restrict__ x4 = (const f32x4*)(logits + (size_t)row * CC);

    __shared__ int s_lab;
    __shared__ float s_sum[BLK / 64];

    if (tid == 0) s_lab = -1;
    __syncthreads();
    volatile int* vlab = &s_lab;

    // ---- phase A: early-exit one-hot scan, 2 loads in flight per poll ----
    #pragma unroll 1
    for (int i = tid; i < C4; i += 2 * BLK) {
        const int j = i + BLK;
        const u32x4 u1 = __builtin_nontemporal_load(&y4[i]);
        u32x4 u2 = {0u, 0u, 0u, 0u};
        if (j < C4) u2 = __builtin_nontemporal_load(&y4[j]);
        if (*vlab >= 0) break;             // poll overlaps the loads above
        if (u1.x | u1.y | u1.z | u1.w) {
            const int off = u1.x ? 0 : (u1.y ? 1 : (u1.z ? 2 : 3));
            *vlab = 4 * i + off;           // exactly one finder per row
        }
        if (u2.x | u2.y | u2.z | u2.w) {
            const int off = u2.x ? 0 : (u2.y ? 1 : (u2.z ? 2 : 3));
            *vlab = 4 * j + off;
        }
    }
    __syncthreads();
    const int lab = s_lab;

    // scalar load of the label logit; consumed only in the epilogue, so its
    // latency hides under all of phase B
    float val = 0.0f;
    if (tid == 0) val = logits[(size_t)row * CC + lab];

    // ---- phase B: exp-sum over x (pure stream, normal loads -> L3 resident) ----
    float s0 = 0.0f, s1 = 0.0f;
    #pragma unroll 1
    for (int i = tid; i < C4; i += BLK) {
        const f32x4 x = x4[i];
        s0 += e64(x.x); s1 += e64(x.y); s0 += e64(x.z); s1 += e64(x.w);
    }

    float s = wave_reduce_add(s0 + s1);
    if ((tid & 63) == 0) s_sum[tid >> 6] = s;
    __syncthreads();

    if (tid == 0) {
        float total = 0.0f;
        #pragma unroll
        for (int w = 0; w < BLK / 64; ++w) total += s_sum[w];

        // margin1=1, margin2=0.5, margin3=0
        const float THRESH = -0.8775825618903728f;  // cos(pi - 0.5)
        const float theta = cosf(acosf(val) + 0.5f);
        const float tv = (val > THRESH) ? theta : (-2.0f - theta);

        // swap label term: remove exp(64v-64), add exp(64*tv-64)
        total += e64(tv) - e64(val);

        // loss_b = (64 + log(total)) - 64*tv ; contribute loss_b/B to the mean
        const float loss = 64.0f + logf(total) - 64.0f * tv;
        atomicAdd(out, loss * (1.0f / (float)BB));   // device-scope by default
    }
}

extern "C" void kernel_launch(void* const* d_in, const int* in_sizes, int n_in,
                              void* d_out, int out_size, void* d_ws, size_t ws_size,
                              hipStream_t stream) {
    const float* y_true = (const float*)d_in[0];
    const float* logits = (const float*)d_in[1];
    float* out = (float*)d_out;

    hipMemsetAsync(out, 0, sizeof(float), stream);   // graph memset node
    arcface_rows<<<BB, BLK, 0, stream>>>(y_true, logits, out);
}